// Round 1
// 513.138 us; speedup vs baseline: 1.0008x; 1.0008x over previous
//
#include <hip/hip_runtime.h>

// out[b, bin, d] = ce[chr[b]-1, d]; tensor (512,2001) unused, chr (512,) i32,
// ce (24,128) f32, out (512,2001,128) f32 = 524.5 MB. Pure write-BW-bound.
//
// v4: match the rocclr fill kernel's store pattern (it demonstrates 6.27 TB/s
// on this chip in this very run):
//   - PLAIN stores, not nontemporal (no reuse to protect; fill uses plain).
//   - one 64-bit address per loop iteration; the 4 stores are at immediate
//     offsets 0/1024/2048/3072 (13-bit signed range), so each iter is
//     1 addr-calc + 4x global_store_dwordx4.
//   - each wave owns an 8-bin (4 KB) group per step: lanes 0..63 * 16B cover
//     2 bins contiguously per instruction (1 KB/instr, fully coalesced).

constexpr int NBINS   = 2001;            // BIN_SIZE + 1
constexpr int DIM     = 128;
constexpr int CHUNKS  = 4;               // group-range chunks -> 2048 blocks
constexpr int NGROUPS = (NBINS + 7) / 8; // 251 8-bin groups (last partial)

typedef float v4f __attribute__((ext_vector_type(4)));

__global__ __launch_bounds__(256) void chrom_embed_bcast(
    const int* __restrict__ chr,
    const float* __restrict__ ce,
    float* __restrict__ out,
    int groups_per_chunk)
{
    const int b    = blockIdx.y;          // sample 0..511
    const int row  = chr[b] - 1;          // 0..23
    const int lane = threadIdx.x & 63;
    const int wid  = threadIdx.x >> 6;    // wave 0..3

    // lane's 16B slot within a 512B bin-row (lanes 0..31 -> bin g*8+2k,
    // lanes 32..63 -> bin g*8+2k+1; same d-slot every 1024B).
    const v4f val = ((const v4f*)(ce + (size_t)row * DIM))[lane & 31];

    int g_start = blockIdx.x * groups_per_chunk;
    int g_end   = g_start + groups_per_chunk;
    if (g_end > NGROUPS) g_end = NGROUPS;

    char* out_b = (char*)(out + (size_t)b * NBINS * DIM);

    for (int g = g_start + wid; g < g_end; g += 4) {
        char* p = out_b + (size_t)g * 4096 + lane * 16;
        if (g * 8 + 8 <= NBINS) {
            // full 8-bin group: 4 KB from this wave, immediate-offset stores
            *(v4f*)(p)        = val;
            *(v4f*)(p + 1024) = val;
            *(v4f*)(p + 2048) = val;
            *(v4f*)(p + 3072) = val;
        } else {
            // single partial group at the end (g == 250: bin 2000 only)
            for (int i = 0; i < 4; ++i) {
                int bin = g * 8 + i * 2 + (lane >> 5);
                if (bin < NBINS)
                    *(v4f*)(out_b + (size_t)bin * 512 + (lane & 31) * 16) = val;
            }
        }
    }
}

extern "C" void kernel_launch(void* const* d_in, const int* in_sizes, int n_in,
                              void* d_out, int out_size, void* d_ws, size_t ws_size,
                              hipStream_t stream)
{
    // setup_inputs order: tensor (unused), chr, ce
    const int*   chr = (const int*)d_in[1];
    const float* ce  = (const float*)d_in[2];
    float*       out = (float*)d_out;

    const int bs  = in_sizes[1];                              // 512
    const int gpc = (NGROUPS + CHUNKS - 1) / CHUNKS;          // 63

    dim3 grid(CHUNKS, bs);
    chrom_embed_bcast<<<grid, 256, 0, stream>>>(chr, ce, out, gpc);
}